// Round 4
// baseline (793.940 us; speedup 1.0000x reference)
//
#include <hip/hip_runtime.h>
#include <hip/hip_bf16.h>

// GCN: h = (0.5A)^2 x ; h = relu(h W1 + b1) ; h = (0.5A)^2 h ; h = h W2 + b2
// Rewrites:
//  - (0.5A)^2 (relu(...)) W2 + b2 == (0.5A)^2 (relu(...) W2) + b2
//  - SpMMs via on-device CSR, gather-side, zero float atomics
//  - dense layer: row-per-lane (wave-uniform W reads)
//  - CSR build: two-phase bucketed scatter (r3's direct scatter was
//    partial-line-writeback bound: WRITE_SIZE 100 MB for 12.8 MB payload).
//    Bucket = 128 rows; stage pass appends to 782 advancing pointers
//    (L2-resident write window), bin pass re-scatters within 16 KB spans.
// Buffer plan (ping-pong, d_out used as scratch; staging overlaps B):
//  s1 spmm32: x -> d_out ; s2 spmm32: d_out -> B ; s3 dense: B -> d_out
//  s4 spmm64: d_out -> B ; s5 spmm64: B -> d_out (+b2)

#define SCAN_CHUNK 1024
#define BUCKET_SHIFT 7               // 128 rows per bucket
#define COL_MASK 0x1FFFF             // 17 bits, N=100000 < 131072

// ---------------- CSR build ----------------
__global__ void hist_kernel(const int* __restrict__ er, int E, int* __restrict__ cnt) {
    int i = blockIdx.x * blockDim.x + threadIdx.x;
    int stride = gridDim.x * blockDim.x;
    for (; i < E; i += stride) atomicAdd(&cnt[er[i]], 1);
}

__global__ void scan_pass1(const int* __restrict__ cnt, int N,
                           int* __restrict__ excl, int* __restrict__ blockSums) {
    __shared__ int sdata[256];
    int t = threadIdx.x;
    int base = blockIdx.x * SCAN_CHUNK + t * 4;
    int v0 = (base + 0 < N) ? cnt[base + 0] : 0;
    int v1 = (base + 1 < N) ? cnt[base + 1] : 0;
    int v2 = (base + 2 < N) ? cnt[base + 2] : 0;
    int v3 = (base + 3 < N) ? cnt[base + 3] : 0;
    int tsum = v0 + v1 + v2 + v3;
    sdata[t] = tsum;
    __syncthreads();
    for (int off = 1; off < 256; off <<= 1) {
        int x = (t >= off) ? sdata[t - off] : 0;
        __syncthreads();
        sdata[t] += x;
        __syncthreads();
    }
    int texcl = sdata[t] - tsum;
    if (t == 255) blockSums[blockIdx.x] = sdata[255];
    if (base + 0 < N) excl[base + 0] = texcl;
    if (base + 1 < N) excl[base + 1] = texcl + v0;
    if (base + 2 < N) excl[base + 2] = texcl + v0 + v1;
    if (base + 3 < N) excl[base + 3] = texcl + v0 + v1 + v2;
}

// one-block LDS scan over block sums (nb <= 128 here: 98 blocks at N=100000)
__global__ void scan_pass2(int* __restrict__ bs, int nb) {
    __shared__ int s[128];
    int t = threadIdx.x;
    if (nb <= 128) {
        int v = (t < nb) ? bs[t] : 0;
        s[t] = v;
        __syncthreads();
        for (int off = 1; off < 128; off <<= 1) {
            int x = (t >= off) ? s[t - off] : 0;
            __syncthreads();
            s[t] += x;
            __syncthreads();
        }
        if (t < nb) bs[t] = s[t] - v;  // exclusive
    } else if (t == 0) {               // fallback (never taken at N=100000)
        int acc = 0;
        for (int i = 0; i < nb; i++) { int x = bs[i]; bs[i] = acc; acc += x; }
    }
}

// finalize row_ptr, init row write-pointers and bucket write-pointers
__global__ void scan_pass3(int* __restrict__ row_ptr, const int* __restrict__ blockOff,
                           int* __restrict__ wp, int* __restrict__ bwp, int N, int E) {
    int i = blockIdx.x * blockDim.x + threadIdx.x;
    if (i < N) {
        int v = row_ptr[i] + blockOff[i / SCAN_CHUNK];
        row_ptr[i] = v;
        wp[i] = v;
        if ((i & ((1 << BUCKET_SHIFT) - 1)) == 0) bwp[i >> BUCKET_SHIFT] = v;
    }
    if (i == 0) row_ptr[N] = E;
}

// stage pass: append edge to its bucket region (advancing pointers -> L2-resident
// write lines). Pack local row (7b) above col (17b); val pre-scaled by 0.5.
__global__ void stage_kernel(const int* __restrict__ er, const int* __restrict__ ec,
                             const float* __restrict__ ev, int E,
                             int* __restrict__ bwp, int2* __restrict__ stage) {
    int i = blockIdx.x * blockDim.x + threadIdx.x;
    int stride = gridDim.x * blockDim.x;
    for (; i < E; i += stride) {
        int r = er[i];
        int b = r >> BUCKET_SHIFT;
        int q = atomicAdd(&bwp[b], 1);
        int2 e;
        e.x = ec[i] | ((r & ((1 << BUCKET_SHIFT) - 1)) << 17);
        e.y = __float_as_int(0.5f * ev[i]);
        stage[q] = e;
    }
}

// bin pass: one block per bucket; re-scatter staged edges to exact row slots.
// Writes confined to the bucket's ~16 KB span of cv -> full-line flush.
__global__ void bin_kernel(const int2* __restrict__ stage,
                           const int* __restrict__ row_ptr,
                           int* __restrict__ wp, int2* __restrict__ cv,
                           int N, int E) {
    int b = blockIdx.x;
    int rbase = b << BUCKET_SHIFT;
    if (rbase >= N) return;
    int rtop = rbase + (1 << BUCKET_SHIFT);
    if (rtop > N) rtop = N;
    int start = row_ptr[rbase];
    int end   = row_ptr[rtop];     // row_ptr[N] == E
    for (int q = start + threadIdx.x; q < end; q += blockDim.x) {
        int2 e = stage[q];
        int r = rbase + (e.x >> 17);
        int p = atomicAdd(&wp[r], 1);
        int2 o;
        o.x = e.x & COL_MASK;
        o.y = e.y;
        cv[p] = o;
    }
}

// ---------------- CSR SpMM, gather-side ----------------
template <int D>
__global__ void spmm_csr_kernel(const float* __restrict__ h,
                                const int* __restrict__ row_ptr,
                                const int2* __restrict__ cv,
                                float* __restrict__ out,
                                const float* __restrict__ bias,  // nullable
                                int N) {
    constexpr int LPR = D / 4;
    int gid = blockIdx.x * blockDim.x + threadIdx.x;
    int row = gid / LPR;
    int sub = gid % LPR;
    if (row >= N) return;
    int start = row_ptr[row];
    int end   = row_ptr[row + 1];
    float4 acc = make_float4(0.f, 0.f, 0.f, 0.f);
    int j = start;
    for (; j + 4 <= end; j += 4) {
        int2 e0 = cv[j], e1 = cv[j + 1], e2 = cv[j + 2], e3 = cv[j + 3];
        float4 h0 = reinterpret_cast<const float4*>(h + (long long)e0.x * D)[sub];
        float4 h1 = reinterpret_cast<const float4*>(h + (long long)e1.x * D)[sub];
        float4 h2 = reinterpret_cast<const float4*>(h + (long long)e2.x * D)[sub];
        float4 h3 = reinterpret_cast<const float4*>(h + (long long)e3.x * D)[sub];
        float v0 = __int_as_float(e0.y), v1 = __int_as_float(e1.y);
        float v2 = __int_as_float(e2.y), v3 = __int_as_float(e3.y);
        acc.x = fmaf(v0, h0.x, acc.x); acc.y = fmaf(v0, h0.y, acc.y);
        acc.z = fmaf(v0, h0.z, acc.z); acc.w = fmaf(v0, h0.w, acc.w);
        acc.x = fmaf(v1, h1.x, acc.x); acc.y = fmaf(v1, h1.y, acc.y);
        acc.z = fmaf(v1, h1.z, acc.z); acc.w = fmaf(v1, h1.w, acc.w);
        acc.x = fmaf(v2, h2.x, acc.x); acc.y = fmaf(v2, h2.y, acc.y);
        acc.z = fmaf(v2, h2.z, acc.z); acc.w = fmaf(v2, h2.w, acc.w);
        acc.x = fmaf(v3, h3.x, acc.x); acc.y = fmaf(v3, h3.y, acc.y);
        acc.z = fmaf(v3, h3.z, acc.z); acc.w = fmaf(v3, h3.w, acc.w);
    }
    for (; j < end; j++) {
        int2 e = cv[j];
        float v = __int_as_float(e.y);
        float4 hv = reinterpret_cast<const float4*>(h + (long long)e.x * D)[sub];
        acc.x = fmaf(v, hv.x, acc.x); acc.y = fmaf(v, hv.y, acc.y);
        acc.z = fmaf(v, hv.z, acc.z); acc.w = fmaf(v, hv.w, acc.w);
    }
    if (bias) {
        acc.x += bias[sub * 4 + 0];
        acc.y += bias[sub * 4 + 1];
        acc.z += bias[sub * 4 + 2];
        acc.w += bias[sub * 4 + 3];
    }
    reinterpret_cast<float4*>(out + (long long)row * D)[sub] = acc;
}

// ---------------- fused dense: out = relu(h@W1 + b1) @ W2, row-per-lane ------
__global__ __launch_bounds__(256) void dense_fused_kernel(
        const float* __restrict__ h,   // [N,32]
        const float* __restrict__ W1,  // [32,64]
        const float* __restrict__ b1,  // [64]
        const float* __restrict__ W2,  // [64,64]
        float* __restrict__ out, int N) {
    __shared__ float buf[4 * 64 * 64];  // 64 KB: per-wave 4096-float tile
    int tid = threadIdx.x;
    int lane = tid & 63;
    int wave = tid >> 6;
    float* wbuf = &buf[wave * 4096];

    int rowbase = blockIdx.x * 256 + wave * 64;
    if (rowbase >= N) return;           // wave-uniform
    int row = rowbase + lane;
    bool valid = row < N;

    {   // cooperative, coalesced h stage: 64 rows x 32 floats contiguous
        const float* src = h + (long long)rowbase * 32;
        int maxf = (N - rowbase) * 32;
#pragma unroll
        for (int i = 0; i < 8; i++) {
            int f = i * 256 + lane * 4;
            int fc = (f + 4 <= maxf) ? f : (maxf >= 4 ? maxf - 4 : 0);
            float4 a = reinterpret_cast<const float4*>(src + fc)[0];
            int r = fc >> 5, k = fc & 31;
            float* dst = wbuf + r * 33 + k;
            dst[0] = a.x; dst[1] = a.y; dst[2] = a.z; dst[3] = a.w;
        }
    }

    float u[64];
#pragma unroll
    for (int j = 0; j < 64; j++) u[j] = b1[j];
    for (int k = 0; k < 32; k++) {
        float hk = wbuf[lane * 33 + k];
        const float* w1r = W1 + k * 64;
#pragma unroll
        for (int j = 0; j < 64; j++) u[j] = fmaf(hk, w1r[j], u[j]);
    }
#pragma unroll
    for (int j = 0; j < 64; j++) u[j] = fmaxf(u[j], 0.0f);

#pragma unroll
    for (int j = 0; j < 64; j++) wbuf[lane * 64 + ((j + lane) & 63)] = u[j];

    float v[64];
#pragma unroll
    for (int j = 0; j < 64; j++) v[j] = 0.0f;
    for (int k = 0; k < 64; k++) {
        float uk = wbuf[lane * 64 + ((k + lane) & 63)];
        const float* w2r = W2 + k * 64;
#pragma unroll
        for (int j = 0; j < 64; j++) v[j] = fmaf(uk, w2r[j], v[j]);
    }

    if (valid) {
        float4* op = reinterpret_cast<float4*>(out + (long long)row * 64);
#pragma unroll
        for (int m = 0; m < 16; m++) {
            float4 o;
            o.x = v[m * 4 + 0]; o.y = v[m * 4 + 1];
            o.z = v[m * 4 + 2]; o.w = v[m * 4 + 3];
            op[m] = o;
        }
    }
}

extern "C" void kernel_launch(void* const* d_in, const int* in_sizes, int n_in,
                              void* d_out, int out_size, void* d_ws, size_t ws_size,
                              hipStream_t stream) {
    const float* x        = (const float*)d_in[0];
    const float* edge_val = (const float*)d_in[1];
    const int*   edge_row = (const int*)d_in[2];
    const int*   edge_col = (const int*)d_in[3];
    const float* W1       = (const float*)d_in[4];
    const float* b1       = (const float*)d_in[5];
    const float* W2       = (const float*)d_in[6];
    const float* b2       = (const float*)d_in[7];
    float* out = (float*)d_out;

    const int N = in_sizes[0] / 32;   // 100000
    const int E = in_sizes[1];        // 1600000
    const int NB = (N + (1 << BUCKET_SHIFT) - 1) >> BUCKET_SHIFT;  // 782

    // ws layout (staging overlaps B: staging dead before B is first written)
    float* B         = (float*)d_ws;                  // N*64 floats (ping buffer)
    int2*  stage     = (int2*)d_ws;                   // E int2 (12.8 MB <= 25.6 MB)
    int*   row_ptr   = (int*)(B + (size_t)N * 64);    // N+1
    int*   wp        = row_ptr + (N + 1);             // N
    int*   bwp       = wp + N;                        // NB
    int*   blockSums = bwp + NB;                      // 256
    size_t cvOff = (size_t)((char*)(blockSums + 256) - (char*)d_ws);
    cvOff = (cvOff + 7) & ~(size_t)7;
    int2* cv = (int2*)((char*)d_ws + cvOff);          // E packed edges

    const int BLK = 256;
    int nScanBlocks = (N + SCAN_CHUNK - 1) / SCAN_CHUNK;

    // ---- CSR build ----
    hipMemsetAsync(wp, 0, (size_t)N * sizeof(int), stream);
    hist_kernel<<<(E + BLK - 1) / BLK, BLK, 0, stream>>>(edge_row, E, wp);
    scan_pass1<<<nScanBlocks, 256, 0, stream>>>(wp, N, row_ptr, blockSums);
    scan_pass2<<<1, 128, 0, stream>>>(blockSums, nScanBlocks);
    scan_pass3<<<(N + BLK - 1) / BLK, BLK, 0, stream>>>(row_ptr, blockSums, wp, bwp, N, E);
    stage_kernel<<<(E + BLK - 1) / BLK, BLK, 0, stream>>>(edge_row, edge_col, edge_val,
                                                          E, bwp, stage);
    bin_kernel<<<NB, BLK, 0, stream>>>(stage, row_ptr, wp, cv, N, E);

    // ---- pipeline ----
    int g32 = ((N * 8)  + BLK - 1) / BLK;   // D=32: 8 lanes/row
    int g64 = ((N * 16) + BLK - 1) / BLK;   // D=64: 16 lanes/row

    spmm_csr_kernel<32><<<g32, BLK, 0, stream>>>(x, row_ptr, cv, out, nullptr, N);
    spmm_csr_kernel<32><<<g32, BLK, 0, stream>>>(out, row_ptr, cv, B, nullptr, N);
    dense_fused_kernel<<<(N + 255) / 256, 256, 0, stream>>>(B, W1, b1, W2, out, N);
    spmm_csr_kernel<64><<<g64, BLK, 0, stream>>>(out, row_ptr, cv, B, nullptr, N);
    spmm_csr_kernel<64><<<g64, BLK, 0, stream>>>(B, row_ptr, cv, out, b2, N);
}

// Round 5
// 535.160 us; speedup vs baseline: 1.4836x; 1.4836x over previous
//
#include <hip/hip_runtime.h>
#include <hip/hip_bf16.h>

// GCN: h = (0.5A)^2 x ; h = relu(h W1 + b1) ; h = (0.5A)^2 h ; h = h W2 + b2
// Rewrites:
//  - (0.5A)^2 (relu(...)) W2 + b2 == (0.5A)^2 (relu(...) W2) + b2
//  - SpMMs via on-device CSR, gather-side, zero float atomics
//  - dense layer: row-per-lane (wave-uniform W reads)
//  - CSR build: two-phase bucketed scatter.
//    r3 direct scatter: partial-line writeback bound (100 MB WRITE for 12.8 MB).
//    r4 bucket=128: atomic-line contention (782 counters = 49 lines -> 375 us).
//    r5: bucket=8 rows (12.5K buckets) + counters PADDED one per 64B line ->
//        same-address contention only (~128 atomics/addr ~ 1.5 us), write
//        window ~800 KB (L2-resident, full-line flush preserved).
// Buffer plan (ping-pong, d_out used as scratch; staging overlaps B):
//  s1 spmm32: x -> d_out ; s2 spmm32: d_out -> B ; s3 dense: B -> d_out
//  s4 spmm64: d_out -> B ; s5 spmm64: B -> d_out (+b2)

#define SCAN_CHUNK 1024
#define BUCKET_SHIFT 3               // 8 rows per bucket
#define BWP_STRIDE 16                // pad bucket counters: 1 per 64B line
#define COL_MASK 0x1FFFF             // 17 bits, N=100000 < 131072

// ---------------- CSR build ----------------
__global__ void hist_kernel(const int* __restrict__ er, int E, int* __restrict__ cnt) {
    int i = blockIdx.x * blockDim.x + threadIdx.x;
    int stride = gridDim.x * blockDim.x;
    for (; i < E; i += stride) atomicAdd(&cnt[er[i]], 1);
}

__global__ void scan_pass1(const int* __restrict__ cnt, int N,
                           int* __restrict__ excl, int* __restrict__ blockSums) {
    __shared__ int sdata[256];
    int t = threadIdx.x;
    int base = blockIdx.x * SCAN_CHUNK + t * 4;
    int v0 = (base + 0 < N) ? cnt[base + 0] : 0;
    int v1 = (base + 1 < N) ? cnt[base + 1] : 0;
    int v2 = (base + 2 < N) ? cnt[base + 2] : 0;
    int v3 = (base + 3 < N) ? cnt[base + 3] : 0;
    int tsum = v0 + v1 + v2 + v3;
    sdata[t] = tsum;
    __syncthreads();
    for (int off = 1; off < 256; off <<= 1) {
        int x = (t >= off) ? sdata[t - off] : 0;
        __syncthreads();
        sdata[t] += x;
        __syncthreads();
    }
    int texcl = sdata[t] - tsum;
    if (t == 255) blockSums[blockIdx.x] = sdata[255];
    if (base + 0 < N) excl[base + 0] = texcl;
    if (base + 1 < N) excl[base + 1] = texcl + v0;
    if (base + 2 < N) excl[base + 2] = texcl + v0 + v1;
    if (base + 3 < N) excl[base + 3] = texcl + v0 + v1 + v2;
}

// one-block LDS scan over block sums (98 blocks at N=100000)
__global__ void scan_pass2(int* __restrict__ bs, int nb) {
    __shared__ int s[128];
    int t = threadIdx.x;
    if (nb <= 128) {
        int v = (t < nb) ? bs[t] : 0;
        s[t] = v;
        __syncthreads();
        for (int off = 1; off < 128; off <<= 1) {
            int x = (t >= off) ? s[t - off] : 0;
            __syncthreads();
            s[t] += x;
            __syncthreads();
        }
        if (t < nb) bs[t] = s[t] - v;  // exclusive
    } else if (t == 0) {               // fallback (never taken at N=100000)
        int acc = 0;
        for (int i = 0; i < nb; i++) { int x = bs[i]; bs[i] = acc; acc += x; }
    }
}

// finalize row_ptr, init row write-pointers and (padded) bucket write-pointers
__global__ void scan_pass3(int* __restrict__ row_ptr, const int* __restrict__ blockOff,
                           int* __restrict__ wp, int* __restrict__ bwp, int N, int E) {
    int i = blockIdx.x * blockDim.x + threadIdx.x;
    if (i < N) {
        int v = row_ptr[i] + blockOff[i / SCAN_CHUNK];
        row_ptr[i] = v;
        wp[i] = v;
        if ((i & ((1 << BUCKET_SHIFT) - 1)) == 0)
            bwp[(i >> BUCKET_SHIFT) * BWP_STRIDE] = v;
    }
    if (i == 0) row_ptr[N] = E;
}

// stage pass: append edge to its bucket region. Counters padded one/line ->
// only same-address atomic serialization (~128/addr). Pack local row (3b)
// above col (17b); val pre-scaled by 0.5.
__global__ void stage_kernel(const int* __restrict__ er, const int* __restrict__ ec,
                             const float* __restrict__ ev, int E,
                             int* __restrict__ bwp, int2* __restrict__ stage) {
    int i = blockIdx.x * blockDim.x + threadIdx.x;
    int stride = gridDim.x * blockDim.x;
    for (; i < E; i += stride) {
        int r = er[i];
        int b = r >> BUCKET_SHIFT;
        int q = atomicAdd(&bwp[b * BWP_STRIDE], 1);
        int2 e;
        e.x = ec[i] | ((r & ((1 << BUCKET_SHIFT) - 1)) << 17);
        e.y = __float_as_int(0.5f * ev[i]);
        stage[q] = e;
    }
}

// bin pass: one block per bucket; re-scatter staged edges to exact row slots.
// Writes confined to the bucket's ~1 KB span of cv -> full-line flush.
__global__ void bin_kernel(const int2* __restrict__ stage,
                           const int* __restrict__ row_ptr,
                           int* __restrict__ wp, int2* __restrict__ cv, int N) {
    int b = blockIdx.x;
    int rbase = b << BUCKET_SHIFT;
    if (rbase >= N) return;
    int rtop = rbase + (1 << BUCKET_SHIFT);
    if (rtop > N) rtop = N;
    int start = row_ptr[rbase];
    int end   = row_ptr[rtop];
    for (int q = start + threadIdx.x; q < end; q += blockDim.x) {
        int2 e = stage[q];
        int r = rbase + (e.x >> 17);
        int p = atomicAdd(&wp[r], 1);
        int2 o;
        o.x = e.x & COL_MASK;
        o.y = e.y;
        cv[p] = o;
    }
}

// ---------------- CSR SpMM, gather-side ----------------
template <int D>
__global__ void spmm_csr_kernel(const float* __restrict__ h,
                                const int* __restrict__ row_ptr,
                                const int2* __restrict__ cv,
                                float* __restrict__ out,
                                const float* __restrict__ bias,  // nullable
                                int N) {
    constexpr int LPR = D / 4;
    int gid = blockIdx.x * blockDim.x + threadIdx.x;
    int row = gid / LPR;
    int sub = gid % LPR;
    if (row >= N) return;
    int start = row_ptr[row];
    int end   = row_ptr[row + 1];
    float4 acc = make_float4(0.f, 0.f, 0.f, 0.f);
    int j = start;
    for (; j + 4 <= end; j += 4) {
        int2 e0 = cv[j], e1 = cv[j + 1], e2 = cv[j + 2], e3 = cv[j + 3];
        float4 h0 = reinterpret_cast<const float4*>(h + (long long)e0.x * D)[sub];
        float4 h1 = reinterpret_cast<const float4*>(h + (long long)e1.x * D)[sub];
        float4 h2 = reinterpret_cast<const float4*>(h + (long long)e2.x * D)[sub];
        float4 h3 = reinterpret_cast<const float4*>(h + (long long)e3.x * D)[sub];
        float v0 = __int_as_float(e0.y), v1 = __int_as_float(e1.y);
        float v2 = __int_as_float(e2.y), v3 = __int_as_float(e3.y);
        acc.x = fmaf(v0, h0.x, acc.x); acc.y = fmaf(v0, h0.y, acc.y);
        acc.z = fmaf(v0, h0.z, acc.z); acc.w = fmaf(v0, h0.w, acc.w);
        acc.x = fmaf(v1, h1.x, acc.x); acc.y = fmaf(v1, h1.y, acc.y);
        acc.z = fmaf(v1, h1.z, acc.z); acc.w = fmaf(v1, h1.w, acc.w);
        acc.x = fmaf(v2, h2.x, acc.x); acc.y = fmaf(v2, h2.y, acc.y);
        acc.z = fmaf(v2, h2.z, acc.z); acc.w = fmaf(v2, h2.w, acc.w);
        acc.x = fmaf(v3, h3.x, acc.x); acc.y = fmaf(v3, h3.y, acc.y);
        acc.z = fmaf(v3, h3.z, acc.z); acc.w = fmaf(v3, h3.w, acc.w);
    }
    for (; j < end; j++) {
        int2 e = cv[j];
        float v = __int_as_float(e.y);
        float4 hv = reinterpret_cast<const float4*>(h + (long long)e.x * D)[sub];
        acc.x = fmaf(v, hv.x, acc.x); acc.y = fmaf(v, hv.y, acc.y);
        acc.z = fmaf(v, hv.z, acc.z); acc.w = fmaf(v, hv.w, acc.w);
    }
    if (bias) {
        acc.x += bias[sub * 4 + 0];
        acc.y += bias[sub * 4 + 1];
        acc.z += bias[sub * 4 + 2];
        acc.w += bias[sub * 4 + 3];
    }
    reinterpret_cast<float4*>(out + (long long)row * D)[sub] = acc;
}

// ---------------- fused dense: out = relu(h@W1 + b1) @ W2, row-per-lane ------
__global__ __launch_bounds__(256) void dense_fused_kernel(
        const float* __restrict__ h,   // [N,32]
        const float* __restrict__ W1,  // [32,64]
        const float* __restrict__ b1,  // [64]
        const float* __restrict__ W2,  // [64,64]
        float* __restrict__ out, int N) {
    __shared__ float buf[4 * 64 * 64];  // 64 KB: per-wave 4096-float tile
    int tid = threadIdx.x;
    int lane = tid & 63;
    int wave = tid >> 6;
    float* wbuf = &buf[wave * 4096];

    int rowbase = blockIdx.x * 256 + wave * 64;
    if (rowbase >= N) return;           // wave-uniform
    int row = rowbase + lane;
    bool valid = row < N;

    {   // cooperative, coalesced h stage: 64 rows x 32 floats contiguous
        const float* src = h + (long long)rowbase * 32;
        int maxf = (N - rowbase) * 32;
#pragma unroll
        for (int i = 0; i < 8; i++) {
            int f = i * 256 + lane * 4;
            int fc = (f + 4 <= maxf) ? f : (maxf >= 4 ? maxf - 4 : 0);
            float4 a = reinterpret_cast<const float4*>(src + fc)[0];
            int r = fc >> 5, k = fc & 31;
            float* dst = wbuf + r * 33 + k;
            dst[0] = a.x; dst[1] = a.y; dst[2] = a.z; dst[3] = a.w;
        }
    }

    float u[64];
#pragma unroll
    for (int j = 0; j < 64; j++) u[j] = b1[j];
    for (int k = 0; k < 32; k++) {
        float hk = wbuf[lane * 33 + k];
        const float* w1r = W1 + k * 64;
#pragma unroll
        for (int j = 0; j < 64; j++) u[j] = fmaf(hk, w1r[j], u[j]);
    }
#pragma unroll
    for (int j = 0; j < 64; j++) u[j] = fmaxf(u[j], 0.0f);

#pragma unroll
    for (int j = 0; j < 64; j++) wbuf[lane * 64 + ((j + lane) & 63)] = u[j];

    float v[64];
#pragma unroll
    for (int j = 0; j < 64; j++) v[j] = 0.0f;
    for (int k = 0; k < 64; k++) {
        float uk = wbuf[lane * 64 + ((k + lane) & 63)];
        const float* w2r = W2 + k * 64;
#pragma unroll
        for (int j = 0; j < 64; j++) v[j] = fmaf(uk, w2r[j], v[j]);
    }

    if (valid) {
        float4* op = reinterpret_cast<float4*>(out + (long long)row * 64);
#pragma unroll
        for (int m = 0; m < 16; m++) {
            float4 o;
            o.x = v[m * 4 + 0]; o.y = v[m * 4 + 1];
            o.z = v[m * 4 + 2]; o.w = v[m * 4 + 3];
            op[m] = o;
        }
    }
}

extern "C" void kernel_launch(void* const* d_in, const int* in_sizes, int n_in,
                              void* d_out, int out_size, void* d_ws, size_t ws_size,
                              hipStream_t stream) {
    const float* x        = (const float*)d_in[0];
    const float* edge_val = (const float*)d_in[1];
    const int*   edge_row = (const int*)d_in[2];
    const int*   edge_col = (const int*)d_in[3];
    const float* W1       = (const float*)d_in[4];
    const float* b1       = (const float*)d_in[5];
    const float* W2       = (const float*)d_in[6];
    const float* b2       = (const float*)d_in[7];
    float* out = (float*)d_out;

    const int N = in_sizes[0] / 32;   // 100000
    const int E = in_sizes[1];        // 1600000
    const int NB = (N + (1 << BUCKET_SHIFT) - 1) >> BUCKET_SHIFT;  // 12500

    // ws layout (staging overlaps B: staging dead before B is first written)
    float* B         = (float*)d_ws;                  // N*64 floats (ping buffer)
    int2*  stage     = (int2*)d_ws;                   // E int2 (12.8 MB <= 25.6 MB)
    int*   row_ptr   = (int*)(B + (size_t)N * 64);    // N+1
    int*   wp        = row_ptr + (N + 1);             // N
    int*   bwp       = wp + N;                        // NB*BWP_STRIDE (padded)
    int*   blockSums = bwp + NB * BWP_STRIDE;         // 256
    size_t cvOff = (size_t)((char*)(blockSums + 256) - (char*)d_ws);
    cvOff = (cvOff + 7) & ~(size_t)7;
    int2* cv = (int2*)((char*)d_ws + cvOff);          // E packed edges

    const int BLK = 256;
    int nScanBlocks = (N + SCAN_CHUNK - 1) / SCAN_CHUNK;

    // ---- CSR build ----
    hipMemsetAsync(wp, 0, (size_t)N * sizeof(int), stream);
    hist_kernel<<<(E + BLK - 1) / BLK, BLK, 0, stream>>>(edge_row, E, wp);
    scan_pass1<<<nScanBlocks, 256, 0, stream>>>(wp, N, row_ptr, blockSums);
    scan_pass2<<<1, 128, 0, stream>>>(blockSums, nScanBlocks);
    scan_pass3<<<(N + BLK - 1) / BLK, BLK, 0, stream>>>(row_ptr, blockSums, wp, bwp, N, E);
    stage_kernel<<<(E + BLK - 1) / BLK, BLK, 0, stream>>>(edge_row, edge_col, edge_val,
                                                          E, bwp, stage);
    bin_kernel<<<NB, 128, 0, stream>>>(stage, row_ptr, wp, cv, N);

    // ---- pipeline ----
    int g32 = ((N * 8)  + BLK - 1) / BLK;   // D=32: 8 lanes/row
    int g64 = ((N * 16) + BLK - 1) / BLK;   // D=64: 16 lanes/row

    spmm_csr_kernel<32><<<g32, BLK, 0, stream>>>(x, row_ptr, cv, out, nullptr, N);
    spmm_csr_kernel<32><<<g32, BLK, 0, stream>>>(out, row_ptr, cv, B, nullptr, N);
    dense_fused_kernel<<<(N + 255) / 256, 256, 0, stream>>>(B, W1, b1, W2, out, N);
    spmm_csr_kernel<64><<<g64, BLK, 0, stream>>>(out, row_ptr, cv, B, nullptr, N);
    spmm_csr_kernel<64><<<g64, BLK, 0, stream>>>(B, row_ptr, cv, out, b2, N);
}

// Round 6
// 377.278 us; speedup vs baseline: 2.1044x; 1.4185x over previous
//
#include <hip/hip_runtime.h>
#include <hip/hip_bf16.h>

// GCN: h = (0.5A)^2 x ; h = relu(h W1 + b1) ; h = (0.5A)^2 h ; h = h W2 + b2
// Rewrites:
//  - (0.5A)^2 (relu(...)) W2 + b2 == (0.5A)^2 (relu(...) W2) + b2
//  - SpMMs via on-device CSR, gather-side, zero float atomics
//  - dense layer: row-per-lane (wave-uniform W reads)
//  - CSR build history:
//    r3 direct scatter: partial-line-writeback bound (100 MB WRITE / 12.8 MB).
//    r4 bucket=128: atomic-line contention (49 lines of counters -> 375 us).
//    r5 bucket=8 + padded counters: fixed atomics, but stage lines still
//       written by ~8 random XCDs each -> cross-XCD partial-line WB, 95 MB.
//    r6 (this): 2-pass radix, SINGLE-WRITER lines everywhere:
//       C1: per-block LDS region hist (no per-edge global atomics)
//       scan196: region offsets
//       C2: block-private contiguous runs per region (full-line WB)
//       D : block-per-region LDS sort -> row_ptr + cv (no global atomics)
//       Old N-wide hist + 3 scan passes deleted (row_ptr built in D).
// Buffer plan (ping-pong, d_out used as scratch; stg overlays B):
//  s1 spmm32: x -> d_out ; s2 spmm32: d_out -> B ; s3 dense: B -> d_out
//  s4 spmm64: d_out -> B ; s5 spmm64: B -> d_out (+b2)

#define REGION_SHIFT 9               // 512 rows per region
#define REGION_SIZE  (1 << REGION_SHIFT)
#define RPAD 16                      // pad region counters: 1 per 64B line
#define COL_MASK 0x1FFFF             // 17 bits, N=100000 < 131072

// ---- C1: per-region edge counts (per-block LDS hist, then 1 add/region) ----
__global__ void region_count_kernel(const int* __restrict__ er, int E,
                                    int* __restrict__ region_cnt, int nreg) {
    __shared__ int hist[256];
    int t = threadIdx.x;
    hist[t] = 0;
    __syncthreads();
    int chunk = (E + gridDim.x - 1) / gridDim.x;
    int s = blockIdx.x * chunk;
    int e = min(E, s + chunk);
    for (int i = s + t; i < e; i += 256)
        atomicAdd(&hist[er[i] >> REGION_SHIFT], 1);
    __syncthreads();
    if (t < nreg && hist[t] > 0) atomicAdd(&region_cnt[t * RPAD], hist[t]);
}

// ---- scan over regions (196 <= 256): region_off (RO) + region_wp (consumed) --
__global__ void region_scan_kernel(const int* __restrict__ region_cnt,
                                   int* __restrict__ region_wp,
                                   int* __restrict__ region_off, int nreg, int E) {
    __shared__ int s[256];
    int t = threadIdx.x;
    int v = (t < nreg) ? region_cnt[t * RPAD] : 0;
    s[t] = v;
    __syncthreads();
    for (int off = 1; off < 256; off <<= 1) {
        int x = (t >= off) ? s[t - off] : 0;
        __syncthreads();
        s[t] += x;
        __syncthreads();
    }
    if (t < nreg) {
        int excl = s[t] - v;
        region_wp[t * RPAD] = excl;
        region_off[t] = excl;
    }
    if (t == 0) region_off[nreg] = E;
}

// ---- C2: coarse scatter into region-major stg; block-private runs ----------
__global__ void coarse_scatter_kernel(const int* __restrict__ er,
                                      const int* __restrict__ ec,
                                      const float* __restrict__ ev, int E,
                                      int* __restrict__ region_wp,
                                      int2* __restrict__ stg, int nreg) {
    __shared__ int hist[256], cnt2[256], gbase[256];
    int t = threadIdx.x;
    hist[t] = 0; cnt2[t] = 0;
    __syncthreads();
    int chunk = (E + gridDim.x - 1) / gridDim.x;
    int s0 = blockIdx.x * chunk;
    int e0 = min(E, s0 + chunk);
    for (int i = s0 + t; i < e0; i += 256)
        atomicAdd(&hist[er[i] >> REGION_SHIFT], 1);
    __syncthreads();
    if (t < nreg)
        gbase[t] = (hist[t] > 0) ? atomicAdd(&region_wp[t * RPAD], hist[t]) : 0;
    __syncthreads();
    for (int i = s0 + t; i < e0; i += 256) {   // chunk is L2-hot on re-read
        int r = er[i];
        int b = r >> REGION_SHIFT;
        int rank = atomicAdd(&cnt2[b], 1);
        int2 rec;
        rec.x = ec[i] | ((r & (REGION_SIZE - 1)) << 17);
        rec.y = __float_as_int(0.5f * ev[i]);
        stg[gbase[b] + rank] = rec;            // block-private run
    }
}

// ---- D: per-region LDS sort -> row_ptr + cv (window L2-private) ------------
__global__ void region_sort_kernel(const int2* __restrict__ stg,
                                   const int* __restrict__ region_off,
                                   int* __restrict__ row_ptr,
                                   int2* __restrict__ cv, int N, int E) {
    __shared__ int hist[REGION_SIZE];
    __shared__ int wp_local[REGION_SIZE];
    __shared__ int psum[256];
    int cb = blockIdx.x;
    int lo = cb << REGION_SHIFT;
    if (lo >= N) return;
    int hi = min(lo + REGION_SIZE, N);
    int cnt = hi - lo;
    int t = threadIdx.x;
    for (int r = t; r < cnt; r += 256) hist[r] = 0;
    __syncthreads();
    int start = region_off[cb];
    int end   = region_off[cb + 1];
    for (int q = start + t; q < end; q += 256)
        atomicAdd(&hist[stg[q].x >> 17], 1);
    __syncthreads();
    // exclusive scan over cnt entries (2 per thread)
    int a0 = (2 * t     < cnt) ? hist[2 * t]     : 0;
    int a1 = (2 * t + 1 < cnt) ? hist[2 * t + 1] : 0;
    psum[t] = a0 + a1;
    __syncthreads();
    for (int off = 1; off < 256; off <<= 1) {
        int x = (t >= off) ? psum[t - off] : 0;
        __syncthreads();
        psum[t] += x;
        __syncthreads();
    }
    int excl = psum[t] - (a0 + a1);
    if (2 * t < cnt) {
        wp_local[2 * t] = start + excl;
        row_ptr[lo + 2 * t] = start + excl;
    }
    if (2 * t + 1 < cnt) {
        wp_local[2 * t + 1] = start + excl + a0;
        row_ptr[lo + 2 * t + 1] = start + excl + a0;
    }
    if (cb == 0 && t == 0) row_ptr[N] = E;
    __syncthreads();
    for (int q = start + t; q < end; q += 256) {  // stg region ~64KB, L2-hot
        int2 e = stg[q];
        int lr = e.x >> 17;
        int p = atomicAdd(&wp_local[lr], 1);      // LDS atomic
        int2 o;
        o.x = e.x & COL_MASK;
        o.y = e.y;
        cv[p] = o;                                 // within private 64KB window
    }
}

// ---------------- CSR SpMM, gather-side ----------------
template <int D>
__global__ void spmm_csr_kernel(const float* __restrict__ h,
                                const int* __restrict__ row_ptr,
                                const int2* __restrict__ cv,
                                float* __restrict__ out,
                                const float* __restrict__ bias,  // nullable
                                int N) {
    constexpr int LPR = D / 4;
    int gid = blockIdx.x * blockDim.x + threadIdx.x;
    int row = gid / LPR;
    int sub = gid % LPR;
    if (row >= N) return;
    int start = row_ptr[row];
    int end   = row_ptr[row + 1];
    float4 acc = make_float4(0.f, 0.f, 0.f, 0.f);
    int j = start;
    for (; j + 4 <= end; j += 4) {
        int2 e0 = cv[j], e1 = cv[j + 1], e2 = cv[j + 2], e3 = cv[j + 3];
        float4 h0 = reinterpret_cast<const float4*>(h + (long long)e0.x * D)[sub];
        float4 h1 = reinterpret_cast<const float4*>(h + (long long)e1.x * D)[sub];
        float4 h2 = reinterpret_cast<const float4*>(h + (long long)e2.x * D)[sub];
        float4 h3 = reinterpret_cast<const float4*>(h + (long long)e3.x * D)[sub];
        float v0 = __int_as_float(e0.y), v1 = __int_as_float(e1.y);
        float v2 = __int_as_float(e2.y), v3 = __int_as_float(e3.y);
        acc.x = fmaf(v0, h0.x, acc.x); acc.y = fmaf(v0, h0.y, acc.y);
        acc.z = fmaf(v0, h0.z, acc.z); acc.w = fmaf(v0, h0.w, acc.w);
        acc.x = fmaf(v1, h1.x, acc.x); acc.y = fmaf(v1, h1.y, acc.y);
        acc.z = fmaf(v1, h1.z, acc.z); acc.w = fmaf(v1, h1.w, acc.w);
        acc.x = fmaf(v2, h2.x, acc.x); acc.y = fmaf(v2, h2.y, acc.y);
        acc.z = fmaf(v2, h2.z, acc.z); acc.w = fmaf(v2, h2.w, acc.w);
        acc.x = fmaf(v3, h3.x, acc.x); acc.y = fmaf(v3, h3.y, acc.y);
        acc.z = fmaf(v3, h3.z, acc.z); acc.w = fmaf(v3, h3.w, acc.w);
    }
    for (; j < end; j++) {
        int2 e = cv[j];
        float v = __int_as_float(e.y);
        float4 hv = reinterpret_cast<const float4*>(h + (long long)e.x * D)[sub];
        acc.x = fmaf(v, hv.x, acc.x); acc.y = fmaf(v, hv.y, acc.y);
        acc.z = fmaf(v, hv.z, acc.z); acc.w = fmaf(v, hv.w, acc.w);
    }
    if (bias) {
        acc.x += bias[sub * 4 + 0];
        acc.y += bias[sub * 4 + 1];
        acc.z += bias[sub * 4 + 2];
        acc.w += bias[sub * 4 + 3];
    }
    reinterpret_cast<float4*>(out + (long long)row * D)[sub] = acc;
}

// ---------------- fused dense: out = relu(h@W1 + b1) @ W2, row-per-lane ------
__global__ __launch_bounds__(256) void dense_fused_kernel(
        const float* __restrict__ h,   // [N,32]
        const float* __restrict__ W1,  // [32,64]
        const float* __restrict__ b1,  // [64]
        const float* __restrict__ W2,  // [64,64]
        float* __restrict__ out, int N) {
    __shared__ float buf[4 * 64 * 64];  // 64 KB: per-wave 4096-float tile
    int tid = threadIdx.x;
    int lane = tid & 63;
    int wave = tid >> 6;
    float* wbuf = &buf[wave * 4096];

    int rowbase = blockIdx.x * 256 + wave * 64;
    if (rowbase >= N) return;           // wave-uniform
    int row = rowbase + lane;
    bool valid = row < N;

    {   // cooperative, coalesced h stage: 64 rows x 32 floats contiguous
        const float* src = h + (long long)rowbase * 32;
        int maxf = (N - rowbase) * 32;
#pragma unroll
        for (int i = 0; i < 8; i++) {
            int f = i * 256 + lane * 4;
            int fc = (f + 4 <= maxf) ? f : (maxf >= 4 ? maxf - 4 : 0);
            float4 a = reinterpret_cast<const float4*>(src + fc)[0];
            int r = fc >> 5, k = fc & 31;
            float* dst = wbuf + r * 33 + k;
            dst[0] = a.x; dst[1] = a.y; dst[2] = a.z; dst[3] = a.w;
        }
    }

    float u[64];
#pragma unroll
    for (int j = 0; j < 64; j++) u[j] = b1[j];
    for (int k = 0; k < 32; k++) {
        float hk = wbuf[lane * 33 + k];
        const float* w1r = W1 + k * 64;
#pragma unroll
        for (int j = 0; j < 64; j++) u[j] = fmaf(hk, w1r[j], u[j]);
    }
#pragma unroll
    for (int j = 0; j < 64; j++) u[j] = fmaxf(u[j], 0.0f);

#pragma unroll
    for (int j = 0; j < 64; j++) wbuf[lane * 64 + ((j + lane) & 63)] = u[j];

    float v[64];
#pragma unroll
    for (int j = 0; j < 64; j++) v[j] = 0.0f;
    for (int k = 0; k < 64; k++) {
        float uk = wbuf[lane * 64 + ((k + lane) & 63)];
        const float* w2r = W2 + k * 64;
#pragma unroll
        for (int j = 0; j < 64; j++) v[j] = fmaf(uk, w2r[j], v[j]);
    }

    if (valid) {
        float4* op = reinterpret_cast<float4*>(out + (long long)row * 64);
#pragma unroll
        for (int m = 0; m < 16; m++) {
            float4 o;
            o.x = v[m * 4 + 0]; o.y = v[m * 4 + 1];
            o.z = v[m * 4 + 2]; o.w = v[m * 4 + 3];
            op[m] = o;
        }
    }
}

extern "C" void kernel_launch(void* const* d_in, const int* in_sizes, int n_in,
                              void* d_out, int out_size, void* d_ws, size_t ws_size,
                              hipStream_t stream) {
    const float* x        = (const float*)d_in[0];
    const float* edge_val = (const float*)d_in[1];
    const int*   edge_row = (const int*)d_in[2];
    const int*   edge_col = (const int*)d_in[3];
    const float* W1       = (const float*)d_in[4];
    const float* b1       = (const float*)d_in[5];
    const float* W2       = (const float*)d_in[6];
    const float* b2       = (const float*)d_in[7];
    float* out = (float*)d_out;

    const int N = in_sizes[0] / 32;   // 100000
    const int E = in_sizes[1];        // 1600000
    const int NREG = (N + REGION_SIZE - 1) >> REGION_SHIFT;  // 196

    // ws layout (stg overlays B: stg dead before B is first written)
    float* B          = (float*)d_ws;                 // N*64 floats (ping buffer)
    int2*  stg        = (int2*)d_ws;                  // E int2 (12.8 MB <= 25.6 MB)
    int*   row_ptr    = (int*)(B + (size_t)N * 64);   // N+1
    int*   region_cnt = row_ptr + (N + 1);            // NREG*RPAD (padded)
    int*   region_wp  = region_cnt + NREG * RPAD;     // NREG*RPAD (padded)
    int*   region_off = region_wp + NREG * RPAD;      // NREG+1
    size_t cvOff = (size_t)((char*)(region_off + NREG + 1) - (char*)d_ws);
    cvOff = (cvOff + 7) & ~(size_t)7;
    int2* cv = (int2*)((char*)d_ws + cvOff);          // E packed edges

    const int BLK = 256;

    // ---- CSR build (2-pass radix, no global atomics on edges) ----
    hipMemsetAsync(region_cnt, 0, (size_t)NREG * RPAD * sizeof(int), stream);
    region_count_kernel<<<256, 256, 0, stream>>>(edge_row, E, region_cnt, NREG);
    region_scan_kernel<<<1, 256, 0, stream>>>(region_cnt, region_wp, region_off,
                                              NREG, E);
    coarse_scatter_kernel<<<NREG, 256, 0, stream>>>(edge_row, edge_col, edge_val,
                                                    E, region_wp, stg, NREG);
    region_sort_kernel<<<NREG, 256, 0, stream>>>(stg, region_off, row_ptr, cv, N, E);

    // ---- pipeline ----
    int g32 = ((N * 8)  + BLK - 1) / BLK;   // D=32: 8 lanes/row
    int g64 = ((N * 16) + BLK - 1) / BLK;   // D=64: 16 lanes/row

    spmm_csr_kernel<32><<<g32, BLK, 0, stream>>>(x, row_ptr, cv, out, nullptr, N);
    spmm_csr_kernel<32><<<g32, BLK, 0, stream>>>(out, row_ptr, cv, B, nullptr, N);
    dense_fused_kernel<<<(N + 255) / 256, 256, 0, stream>>>(B, W1, b1, W2, out, N);
    spmm_csr_kernel<64><<<g64, BLK, 0, stream>>>(out, row_ptr, cv, B, nullptr, N);
    spmm_csr_kernel<64><<<g64, BLK, 0, stream>>>(B, row_ptr, cv, out, b2, N);
}